// Round 1
// baseline (687.799 us; speedup 1.0000x reference)
//
#include <hip/hip_runtime.h>
#include <cstdint>
#include <cstddef>

typedef unsigned short u16;
typedef __bf16 bf16x8 __attribute__((ext_vector_type(8)));
typedef float f32x4 __attribute__((ext_vector_type(4)));
typedef u16 u16x8 __attribute__((ext_vector_type(8)));

typedef const void __attribute__((address_space(1)))* gas_ptr;
typedef void __attribute__((address_space(3)))* las_ptr;

#define TEMP_INV (1.0f / 0.15f)
#define NCH 8
#define CS 512
#define DIM 4096

// RNE float -> bf16
__device__ __forceinline__ u16 f2bf(float f) {
  union { float f; uint32_t u; } a; a.f = f;
  uint32_t r = a.u + 0x7fffu + ((a.u >> 16) & 1u);
  return (u16)(r >> 16);
}

__device__ __forceinline__ float wave_sum(float s) {
  s += __shfl_xor(s, 1);  s += __shfl_xor(s, 2);  s += __shfl_xor(s, 4);
  s += __shfl_xor(s, 8);  s += __shfl_xor(s, 16); s += __shfl_xor(s, 32);
  return s;
}

// ---------------------------------------------------------------------------
// prep_kernel: one launch does everything before the GEMM.
//   blocks 0..7      : full 5-iter sinkhorn for chunk c (E recomputed from L
//                      each pass; L is L2-resident at 1 MB/chunk), emits P bf16.
//   blocks 8..8+2047 : stage1 (chunk-perm applied to x -> Y bf16). The 8x8
//                      chunk perm is recomputed per block (one wave, ~300 cy)
//                      so stage1 has no dependency on the sinkhorn blocks and
//                      the two phases run concurrently on different CUs.
// ---------------------------------------------------------------------------
__global__ __launch_bounds__(1024) void prep_kernel(
    const float* __restrict__ x,
    const float* __restrict__ chunk_logits,
    const float* __restrict__ intra_logits,
    u16* __restrict__ P,     // [8][512][512] bf16 bits
    u16* __restrict__ Y)     // [rows][4096] bf16 bits
{
  __shared__ float u_s[CS];
  __shared__ float v_s[CS];
  __shared__ float ps[8][CS];   // col-pass partials: 8 row-slabs x 512 cols
  __shared__ float cps[64];

  const int bid = blockIdx.x;
  const int tid = threadIdx.x;

  if (bid < NCH) {
    // ---------------- sinkhorn for chunk bid ----------------
    const int c = bid;
    const int wv = tid >> 6, l = tid & 63;   // 16 waves
    const float* Lc = intra_logits + (size_t)c * CS * CS;

    // row pass 0 (v = 1): u = 1/rowsum(exp(L/T))
    for (int r = wv; r < CS; r += 16) {
      const float* Lr = Lc + (size_t)r * CS;
      float s = 0.0f;
      #pragma unroll
      for (int rd = 0; rd < 2; ++rd) {
        const int j = rd * 256 + l * 4;
        float4 t = *(const float4*)(Lr + j);
        s += __expf(t.x * TEMP_INV) + __expf(t.y * TEMP_INV)
           + __expf(t.z * TEMP_INV) + __expf(t.w * TEMP_INV);
      }
      s = wave_sum(s);
      if (l == 0) u_s[r] = 1.0f / s;
    }
    __syncthreads();

    for (int it = 0; it < 5; ++it) {
      // col pass: v = 1/(E^T u). thread owns 4 consecutive cols, 64-row slab.
      {
        const int cq = (tid & 127) * 4, slab = tid >> 7;
        const float* Ls = Lc + (size_t)slab * 64 * CS + cq;
        float ax = 0.f, ay = 0.f, az = 0.f, aw = 0.f;
        #pragma unroll 8
        for (int rr = 0; rr < 64; ++rr) {
          float4 t = *(const float4*)(Ls + (size_t)rr * CS);
          const float uu = u_s[slab * 64 + rr];
          ax += __expf(t.x * TEMP_INV) * uu;
          ay += __expf(t.y * TEMP_INV) * uu;
          az += __expf(t.z * TEMP_INV) * uu;
          aw += __expf(t.w * TEMP_INV) * uu;
        }
        float4 a; a.x = ax; a.y = ay; a.z = az; a.w = aw;
        *(float4*)&ps[slab][cq] = a;
      }
      __syncthreads();
      if (tid < CS) {
        float s = 0.0f;
        #pragma unroll
        for (int sl = 0; sl < 8; ++sl) s += ps[sl][tid];
        v_s[tid] = 1.0f / s;
      }
      __syncthreads();
      if (it == 4) break;
      // row pass: u = 1/(E v)
      for (int r = wv; r < CS; r += 16) {
        const float* Lr = Lc + (size_t)r * CS;
        float s = 0.0f;
        #pragma unroll
        for (int rd = 0; rd < 2; ++rd) {
          const int j = rd * 256 + l * 4;
          float4 t = *(const float4*)(Lr + j);
          float4 v = *(const float4*)(v_s + j);
          s += __expf(t.x * TEMP_INV) * v.x + __expf(t.y * TEMP_INV) * v.y
             + __expf(t.z * TEMP_INV) * v.z + __expf(t.w * TEMP_INV) * v.w;
        }
        s = wave_sum(s);
        if (l == 0) u_s[r] = 1.0f / s;
      }
      __syncthreads();
    }

    // emit P = bf16(E * u * v)
    for (int r = wv; r < CS; r += 16) {
      const float uu = u_s[r];
      const float* Lr = Lc + (size_t)r * CS;
      u16* Pr = P + ((size_t)c * CS + r) * CS;
      const int j0 = l * 8;
      float4 t0 = *(const float4*)(Lr + j0);
      float4 t1 = *(const float4*)(Lr + j0 + 4);
      float4 v0 = *(const float4*)(v_s + j0);
      float4 v1 = *(const float4*)(v_s + j0 + 4);
      u16x8 o;
      o[0] = f2bf(__expf(t0.x * TEMP_INV) * uu * v0.x);
      o[1] = f2bf(__expf(t0.y * TEMP_INV) * uu * v0.y);
      o[2] = f2bf(__expf(t0.z * TEMP_INV) * uu * v0.z);
      o[3] = f2bf(__expf(t0.w * TEMP_INV) * uu * v0.w);
      o[4] = f2bf(__expf(t1.x * TEMP_INV) * uu * v1.x);
      o[5] = f2bf(__expf(t1.y * TEMP_INV) * uu * v1.y);
      o[6] = f2bf(__expf(t1.z * TEMP_INV) * uu * v1.z);
      o[7] = f2bf(__expf(t1.w * TEMP_INV) * uu * v1.w);
      *(u16x8*)(Pr + j0) = o;
    }
    return;
  }

  // ---------------- stage1: Y = (chunk_perm) . x ----------------
  if (tid < 64) {  // wave 0 recomputes the 8x8 chunk perm locally
    float e = __expf(chunk_logits[tid] * TEMP_INV);
    float v = 1.0f, uu = 0.0f;
    #pragma unroll
    for (int it = 0; it < 5; ++it) {
      float t = e * v;
      t += __shfl_xor(t, 1); t += __shfl_xor(t, 2); t += __shfl_xor(t, 4);
      uu = 1.0f / t;
      float t2 = e * uu;
      t2 += __shfl_xor(t2, 8); t2 += __shfl_xor(t2, 16); t2 += __shfl_xor(t2, 32);
      v = 1.0f / t2;
    }
    cps[tid] = e * uu * v;
  }
  __syncthreads();

  const int g  = (bid - NCH) * 1024 + tid;  // over rows*128 float4 slots
  const int b  = g >> 7;
  const int d4 = g & 127;

  const float4* xr = (const float4*)x + (size_t)b * 1024 + d4;
  float4 xi[8];
  #pragma unroll
  for (int jc = 0; jc < 8; ++jc) xi[jc] = xr[(size_t)jc * 128];

  ushort4* yr = (ushort4*)Y + (size_t)b * 1024 + d4;
  #pragma unroll
  for (int i = 0; i < 8; ++i) {
    float ax = 0.f, ay = 0.f, az = 0.f, aw = 0.f;
    #pragma unroll
    for (int jc = 0; jc < 8; ++jc) {
      const float wgt = cps[i * 8 + jc];
      ax += wgt * xi[jc].x; ay += wgt * xi[jc].y;
      az += wgt * xi[jc].z; aw += wgt * xi[jc].w;
    }
    ushort4 o;
    o.x = f2bf(ax); o.y = f2bf(ay); o.z = f2bf(az); o.w = f2bf(aw);
    yr[(size_t)i * 128] = o;
  }
}

// ---------------------------------------------------------------------------
// gemm: out[m, c, n] = sum_k Y[m, c*512+k] * P[c, n, k]
//  - double-buffered 2-phase: issue next-tile global_load_lds BEFORE ds_read+
//    MFMA of current tile; ONE barrier per K-iter (its vmcnt(0) drain is the
//    wait for the prefetch).
//  - XOR swizzle (slot ^= row&3), applied both-sides: pre-swizzled global
//    source column for global_load_lds + swizzled ds_read address (8-way ->
//    4-way bank conflict).
//  - operands swapped: mfma(P_frag, Y_frag) => acc holds out^T fragments:
//    lane = m, reg = 4 consecutive n -> f32x4 nontemporal stores (out is
//    streamed; keep Y/P resident in LLC).
// ---------------------------------------------------------------------------
#define BM 128
#define BN 128
#define BK 32
#define NT (CS / BK)

__global__ __launch_bounds__(256) void gemm_kernel(
    const u16* __restrict__ Y,   // [rows][4096] bf16 bits
    const u16* __restrict__ P,   // [8][512][512] bf16 bits
    float* __restrict__ out)     // [rows][4096] fp32
{
  __shared__ u16 As[2][BM * BK];
  __shared__ u16 Bs[2][BN * BK];

  const int tid = threadIdx.x;
  const int m0 = blockIdx.x * BM;
  const int n0 = blockIdx.y * BN;
  const int c  = blockIdx.z;

  const u16* Ab = Y + (size_t)m0 * DIM + (size_t)c * CS;
  const u16* Bb = P + ((size_t)c * CS + n0) * CS;

  const int w = tid >> 6, l = tid & 63;
  const int wm = (w >> 1) * 64, wn = (w & 1) * 64;
  const int lrow = l & 15, sub = l >> 4;

  f32x4 acc[4][4] = {};

  auto stage = [&](int buf, int kk) {
    #pragma unroll
    for (int rd = 0; rd < 2; ++rd) {
      const int idx = rd * 256 + tid;
      const int r = idx >> 2;
      const int cb = ((idx & 3) ^ (r & 3)) << 3;   // pre-swizzled source col
      __builtin_amdgcn_global_load_lds((gas_ptr)(Ab + (size_t)r * DIM + kk + cb),
                                       (las_ptr)(&As[buf][(idx & ~63) * 8]), 16, 0, 0);
    }
    #pragma unroll
    for (int rd = 0; rd < 2; ++rd) {
      const int idx = rd * 256 + tid;
      const int r = idx >> 2;
      const int cb = ((idx & 3) ^ (r & 3)) << 3;
      __builtin_amdgcn_global_load_lds((gas_ptr)(Bb + (size_t)r * CS + kk + cb),
                                       (las_ptr)(&Bs[buf][(idx & ~63) * 8]), 16, 0, 0);
    }
  };

  stage(0, 0);
  __syncthreads();

  int cur = 0;
  for (int t = 0; t < NT; ++t) {
    if (t + 1 < NT) stage(cur ^ 1, (t + 1) * BK);   // prefetch next tile

    bf16x8 yf[4], pf[4];
    #pragma unroll
    for (int mi = 0; mi < 4; ++mi) {
      const int row = wm + mi * 16 + lrow;
      yf[mi] = *(const bf16x8*)&As[cur][row * BK + ((sub ^ (row & 3)) << 3)];
    }
    #pragma unroll
    for (int ni = 0; ni < 4; ++ni) {
      const int row = wn + ni * 16 + lrow;
      pf[ni] = *(const bf16x8*)&Bs[cur][row * BK + ((sub ^ (row & 3)) << 3)];
    }

    #pragma unroll
    for (int mi = 0; mi < 4; ++mi)
      #pragma unroll
      for (int ni = 0; ni < 4; ++ni)
        acc[mi][ni] = __builtin_amdgcn_mfma_f32_16x16x32_bf16(
            pf[ni], yf[mi], acc[mi][ni], 0, 0, 0);

    __syncthreads();   // drains prefetch (vmcnt 0) + protects LDS reuse
    cur ^= 1;
  }

  // epilogue: acc = out^T fragments; lane&15 = m-row, reg = 4 consecutive n
  const int nq = sub * 4;
  #pragma unroll
  for (int mi = 0; mi < 4; ++mi) {
    const size_t mrow = (size_t)(m0 + wm + mi * 16 + lrow) * DIM + (size_t)c * CS;
    #pragma unroll
    for (int ni = 0; ni < 4; ++ni) {
      __builtin_nontemporal_store(acc[mi][ni],
          (f32x4*)(out + mrow + (size_t)(n0 + wn + ni * 16 + nq)));
    }
  }
}

// ---------------------------------------------------------------------------
// ws layout:
//   [0, 4M)      P bf16   (8*512*512*2)
//   [8M, 136M)   Y bf16   (rows*4096*2)
// ---------------------------------------------------------------------------
extern "C" void kernel_launch(void* const* d_in, const int* in_sizes, int n_in,
                              void* d_out, int out_size, void* d_ws, size_t ws_size,
                              hipStream_t stream) {
  const float* x  = (const float*)d_in[0];
  const float* cl = (const float*)d_in[1];
  const float* il = (const float*)d_in[2];
  float* out = (float*)d_out;

  char* ws = (char*)d_ws;
  u16* P = (u16*)ws;
  u16* Y = (u16*)(ws + (size_t)8 * 1024 * 1024);

  const int rows = in_sizes[0] / DIM;   // 16384

  prep_kernel<<<dim3(NCH + rows / 8), dim3(1024), 0, stream>>>(x, cl, il, P, Y);
  gemm_kernel<<<dim3(rows / BM, CS / BN, NCH), dim3(256), 0, stream>>>(Y, P, out);
}

// Round 2
// 626.765 us; speedup vs baseline: 1.0974x; 1.0974x over previous
//
#include <hip/hip_runtime.h>
#include <cstdint>
#include <cstddef>

typedef unsigned short u16;
typedef __bf16 bf16x8 __attribute__((ext_vector_type(8)));
typedef float f32x4 __attribute__((ext_vector_type(4)));
typedef u16 u16x8 __attribute__((ext_vector_type(8)));

typedef const void __attribute__((address_space(1)))* gas_ptr;
typedef void __attribute__((address_space(3)))* las_ptr;

#define TEMP_INV (1.0f / 0.15f)
#define NCH 8
#define CS 512
#define DIM 4096
#define SINK_BLOCKS 64          // 8 blocks per chunk, 64-row slab each

// RNE float -> bf16
__device__ __forceinline__ u16 f2bf(float f) {
  union { float f; uint32_t u; } a; a.f = f;
  uint32_t r = a.u + 0x7fffu + ((a.u >> 16) & 1u);
  return (u16)(r >> 16);
}

__device__ __forceinline__ float wave_sum(float s) {
  s += __shfl_xor(s, 1);  s += __shfl_xor(s, 2);  s += __shfl_xor(s, 4);
  s += __shfl_xor(s, 8);  s += __shfl_xor(s, 16); s += __shfl_xor(s, 32);
  return s;
}

// ---------------------------------------------------------------------------
// prep_kernel: blocks 0..63 = distributed sinkhorn (8 blocks/chunk, 64-row
// slabs, cross-block v via agent-scope atomicAdd + release/acquire counters).
// blocks 64.. = stage1 (chunk-perm applied to x -> Y bf16), overlapped on the
// remaining CUs. Sinkhorn blocks are dispatched first and finish well inside
// stage1's BW-bound duration.
// ---------------------------------------------------------------------------
__global__ __launch_bounds__(256) void prep_kernel(
    const float* __restrict__ x,
    const float* __restrict__ chunk_logits,
    const float* __restrict__ intra_logits,
    u16* __restrict__ P,        // [8][512][512] bf16 bits
    u16* __restrict__ Y,        // [rows][4096] bf16 bits
    float* __restrict__ vacc,   // [5][8][512] fp32, zeroed per launch
    int* __restrict__ cnt)      // [8][5] arrival counters, zeroed per launch
{
  __shared__ float u_s[64];
  __shared__ float v_s[CS];
  __shared__ float ps2[2][CS];
  __shared__ float cps[64];

  const int bid = blockIdx.x;
  const int tid = threadIdx.x;

  if (bid < SINK_BLOCKS) {
    // ------------- sinkhorn: chunk c, row slab [64s, 64s+64) -------------
    const int c = bid >> 3, s = bid & 7;
    const int wv = tid >> 6, l = tid & 63;
    const float* Ls = intra_logits + ((size_t)c * CS + s * 64) * CS;
    int* cnt_c = cnt + c * 5;

    v_s[tid] = 1.0f; v_s[tid + 256] = 1.0f;
    __syncthreads();

    auto rowpass = [&]() {    // u = 1/(E_slab . v), u in LDS only
      for (int r = wv; r < 64; r += 4) {
        const float* Lr = Ls + (size_t)r * CS;
        float acc = 0.0f;
        #pragma unroll
        for (int rd = 0; rd < 2; ++rd) {
          const int j = rd * 256 + l * 4;
          float4 t = *(const float4*)(Lr + j);
          float4 v = *(const float4*)(v_s + j);
          acc += __expf(t.x * TEMP_INV) * v.x + __expf(t.y * TEMP_INV) * v.y
               + __expf(t.z * TEMP_INV) * v.z + __expf(t.w * TEMP_INV) * v.w;
        }
        acc = wave_sum(acc);
        if (l == 0) u_s[r] = 1.0f / acc;
      }
      __syncthreads();
    };

    rowpass();                 // it0 row pass (v = 1)

    for (int it = 0; it < 5; ++it) {
      // col partials over OWN slab (needs only own u)
      const int half = tid >> 7, ct = tid & 127;
      const float* Lh = Ls + (size_t)half * 32 * CS + ct * 4;
      float ax = 0.f, ay = 0.f, az = 0.f, aw = 0.f;
      #pragma unroll 4
      for (int rr = 0; rr < 32; ++rr) {
        float4 t = *(const float4*)(Lh + (size_t)rr * CS);
        const float uu = u_s[half * 32 + rr];
        ax += __expf(t.x * TEMP_INV) * uu;
        ay += __expf(t.y * TEMP_INV) * uu;
        az += __expf(t.z * TEMP_INV) * uu;
        aw += __expf(t.w * TEMP_INV) * uu;
      }
      float4 a; a.x = ax; a.y = ay; a.z = az; a.w = aw;
      *(float4*)&ps2[half][ct * 4] = a;
      __syncthreads();

      float* va = vacc + ((size_t)it * NCH + c) * CS;
      #pragma unroll
      for (int rep = 0; rep < 2; ++rep) {
        const int j = rep * 256 + tid;
        atomicAdd(&va[j], ps2[0][j] + ps2[1][j]);
      }
      __syncthreads();   // all adds performed (vmcnt drained) before signal

      if (tid == 0) {
        __hip_atomic_fetch_add(&cnt_c[it], 1, __ATOMIC_RELEASE,
                               __HIP_MEMORY_SCOPE_AGENT);
        while (__hip_atomic_load(&cnt_c[it], __ATOMIC_ACQUIRE,
                                 __HIP_MEMORY_SCOPE_AGENT) < 8)
          __builtin_amdgcn_s_sleep(2);
      }
      __syncthreads();

      #pragma unroll
      for (int rep = 0; rep < 2; ++rep) {
        const int j = rep * 256 + tid;
        v_s[j] = 1.0f / __hip_atomic_load(&va[j], __ATOMIC_RELAXED,
                                          __HIP_MEMORY_SCOPE_AGENT);
      }
      __syncthreads();

      if (it < 4) rowpass();
    }

    // emit P = bf16(E * u * v) for own slab
    for (int r = wv; r < 64; r += 4) {
      const float uu = u_s[r];
      const float* Lr = Ls + (size_t)r * CS;
      u16* Pr = P + ((size_t)c * CS + s * 64 + r) * CS;
      const int j0 = l * 8;
      float4 t0 = *(const float4*)(Lr + j0);
      float4 t1 = *(const float4*)(Lr + j0 + 4);
      float4 v0 = *(const float4*)(v_s + j0);
      float4 v1 = *(const float4*)(v_s + j0 + 4);
      u16x8 o;
      o[0] = f2bf(__expf(t0.x * TEMP_INV) * uu * v0.x);
      o[1] = f2bf(__expf(t0.y * TEMP_INV) * uu * v0.y);
      o[2] = f2bf(__expf(t0.z * TEMP_INV) * uu * v0.z);
      o[3] = f2bf(__expf(t0.w * TEMP_INV) * uu * v0.w);
      o[4] = f2bf(__expf(t1.x * TEMP_INV) * uu * v1.x);
      o[5] = f2bf(__expf(t1.y * TEMP_INV) * uu * v1.y);
      o[6] = f2bf(__expf(t1.z * TEMP_INV) * uu * v1.z);
      o[7] = f2bf(__expf(t1.w * TEMP_INV) * uu * v1.w);
      *(u16x8*)(Pr + j0) = o;
    }
    return;
  }

  // ---------------- stage1: Y = (chunk_perm) . x ----------------
  if (tid < 64) {  // wave 0 recomputes the 8x8 chunk perm locally (~300 cy)
    float e = __expf(chunk_logits[tid] * TEMP_INV);
    float v = 1.0f, uu = 0.0f;
    #pragma unroll
    for (int it = 0; it < 5; ++it) {
      float t = e * v;
      t += __shfl_xor(t, 1); t += __shfl_xor(t, 2); t += __shfl_xor(t, 4);
      uu = 1.0f / t;
      float t2 = e * uu;
      t2 += __shfl_xor(t2, 8); t2 += __shfl_xor(t2, 16); t2 += __shfl_xor(t2, 32);
      v = 1.0f / t2;
    }
    cps[tid] = e * uu * v;
  }
  __syncthreads();

  const int g  = (bid - SINK_BLOCKS) * 256 + tid;  // over rows*128 float4 slots
  const int b  = g >> 7;
  const int d4 = g & 127;

  const float4* xr = (const float4*)x + (size_t)b * 1024 + d4;
  float4 xi[8];
  #pragma unroll
  for (int jc = 0; jc < 8; ++jc) xi[jc] = xr[(size_t)jc * 128];

  ushort4* yr = (ushort4*)Y + (size_t)b * 1024 + d4;
  #pragma unroll
  for (int i = 0; i < 8; ++i) {
    float ax = 0.f, ay = 0.f, az = 0.f, aw = 0.f;
    #pragma unroll
    for (int jc = 0; jc < 8; ++jc) {
      const float wgt = cps[i * 8 + jc];
      ax += wgt * xi[jc].x; ay += wgt * xi[jc].y;
      az += wgt * xi[jc].z; aw += wgt * xi[jc].w;
    }
    ushort4 o;
    o.x = f2bf(ax); o.y = f2bf(ay); o.z = f2bf(az); o.w = f2bf(aw);
    yr[(size_t)i * 128] = o;
  }
}

// ---------------------------------------------------------------------------
// gemm: out[m, c, n] = sum_k Y[m, c*512+k] * P[c, n, k]   (unchanged, passing)
//  - double-buffered 2-phase prefetch, one barrier per K-iter
//  - both-sides XOR swizzle (slot ^= row&3)
//  - swapped operands -> f32x4 nontemporal epilogue stores
// ---------------------------------------------------------------------------
#define BM 128
#define BN 128
#define BK 32
#define NT (CS / BK)

__global__ __launch_bounds__(256) void gemm_kernel(
    const u16* __restrict__ Y,   // [rows][4096] bf16 bits
    const u16* __restrict__ P,   // [8][512][512] bf16 bits
    float* __restrict__ out)     // [rows][4096] fp32
{
  __shared__ u16 As[2][BM * BK];
  __shared__ u16 Bs[2][BN * BK];

  const int tid = threadIdx.x;
  const int m0 = blockIdx.x * BM;
  const int n0 = blockIdx.y * BN;
  const int c  = blockIdx.z;

  const u16* Ab = Y + (size_t)m0 * DIM + (size_t)c * CS;
  const u16* Bb = P + ((size_t)c * CS + n0) * CS;

  const int w = tid >> 6, l = tid & 63;
  const int wm = (w >> 1) * 64, wn = (w & 1) * 64;
  const int lrow = l & 15, sub = l >> 4;

  f32x4 acc[4][4] = {};

  auto stage = [&](int buf, int kk) {
    #pragma unroll
    for (int rd = 0; rd < 2; ++rd) {
      const int idx = rd * 256 + tid;
      const int r = idx >> 2;
      const int cb = ((idx & 3) ^ (r & 3)) << 3;   // pre-swizzled source col
      __builtin_amdgcn_global_load_lds((gas_ptr)(Ab + (size_t)r * DIM + kk + cb),
                                       (las_ptr)(&As[buf][(idx & ~63) * 8]), 16, 0, 0);
    }
    #pragma unroll
    for (int rd = 0; rd < 2; ++rd) {
      const int idx = rd * 256 + tid;
      const int r = idx >> 2;
      const int cb = ((idx & 3) ^ (r & 3)) << 3;
      __builtin_amdgcn_global_load_lds((gas_ptr)(Bb + (size_t)r * CS + kk + cb),
                                       (las_ptr)(&Bs[buf][(idx & ~63) * 8]), 16, 0, 0);
    }
  };

  stage(0, 0);
  __syncthreads();

  int cur = 0;
  for (int t = 0; t < NT; ++t) {
    if (t + 1 < NT) stage(cur ^ 1, (t + 1) * BK);   // prefetch next tile

    bf16x8 yf[4], pf[4];
    #pragma unroll
    for (int mi = 0; mi < 4; ++mi) {
      const int row = wm + mi * 16 + lrow;
      yf[mi] = *(const bf16x8*)&As[cur][row * BK + ((sub ^ (row & 3)) << 3)];
    }
    #pragma unroll
    for (int ni = 0; ni < 4; ++ni) {
      const int row = wn + ni * 16 + lrow;
      pf[ni] = *(const bf16x8*)&Bs[cur][row * BK + ((sub ^ (row & 3)) << 3)];
    }

    #pragma unroll
    for (int mi = 0; mi < 4; ++mi)
      #pragma unroll
      for (int ni = 0; ni < 4; ++ni)
        acc[mi][ni] = __builtin_amdgcn_mfma_f32_16x16x32_bf16(
            pf[ni], yf[mi], acc[mi][ni], 0, 0, 0);

    __syncthreads();   // drains prefetch (vmcnt 0) + protects LDS reuse
    cur ^= 1;
  }

  // epilogue: acc = out^T fragments; lane&15 = m-row, reg = 4 consecutive n
  const int nq = sub * 4;
  #pragma unroll
  for (int mi = 0; mi < 4; ++mi) {
    const size_t mrow = (size_t)(m0 + wm + mi * 16 + lrow) * DIM + (size_t)c * CS;
    #pragma unroll
    for (int ni = 0; ni < 4; ++ni) {
      __builtin_nontemporal_store(acc[mi][ni],
          (f32x4*)(out + mrow + (size_t)(n0 + wn + ni * 16 + nq)));
    }
  }
}

// ---------------------------------------------------------------------------
// ws layout:
//   [0, 4M)        P bf16   (8*512*512*2)
//   [4M, 4M+80K)   vacc fp32 [5][8][512]   (zeroed per launch)
//   [4M+80K, +256) cnt  int  [8][5]        (zeroed per launch)
//   [8M, 136M)     Y bf16   (rows*4096*2)
// ---------------------------------------------------------------------------
extern "C" void kernel_launch(void* const* d_in, const int* in_sizes, int n_in,
                              void* d_out, int out_size, void* d_ws, size_t ws_size,
                              hipStream_t stream) {
  const float* x  = (const float*)d_in[0];
  const float* cl = (const float*)d_in[1];
  const float* il = (const float*)d_in[2];
  float* out = (float*)d_out;

  char* ws = (char*)d_ws;
  u16*   P    = (u16*)ws;
  float* vacc = (float*)(ws + (size_t)4 * 1024 * 1024);
  int*   cnt  = (int*)(ws + (size_t)4 * 1024 * 1024 + 80 * 1024);
  u16*   Y    = (u16*)(ws + (size_t)8 * 1024 * 1024);

  const int rows = in_sizes[0] / DIM;   // 16384

  hipMemsetAsync(ws + (size_t)4 * 1024 * 1024, 0, 80 * 1024 + 256, stream);
  prep_kernel<<<dim3(SINK_BLOCKS + rows / 2), dim3(256), 0, stream>>>(
      x, cl, il, P, Y, vacc, cnt);
  gemm_kernel<<<dim3(rows / BM, CS / BN, NCH), dim3(256), 0, stream>>>(Y, P, out);
}